// Round 1
// baseline (254.763 us; speedup 1.0000x reference)
//
#include <hip/hip_runtime.h>

#define BLK 128            // threads per block (2 waves)
#define LS  32             // timesteps per thread-chunk
#define SPB (BLK*LS)       // timesteps per block = 4096
#define SCAN_T 256         // threads in scan block

// ---------- affine step macros (row-major M[16], N[8]) ----------
#define STEP4(Mx,Nx, s0,s1,s2,s3, ux,uy, n0,n1,n2,n3)                                              \
  n0 = fmaf(Mx[0],s0,  fmaf(Mx[1],s1,  fmaf(Mx[2],s2,  fmaf(Mx[3],s3,  fmaf(Nx[0],ux, Nx[1]*uy))))); \
  n1 = fmaf(Mx[4],s0,  fmaf(Mx[5],s1,  fmaf(Mx[6],s2,  fmaf(Mx[7],s3,  fmaf(Nx[2],ux, Nx[3]*uy))))); \
  n2 = fmaf(Mx[8],s0,  fmaf(Mx[9],s1,  fmaf(Mx[10],s2, fmaf(Mx[11],s3, fmaf(Nx[4],ux, Nx[5]*uy))))); \
  n3 = fmaf(Mx[12],s0, fmaf(Mx[13],s1, fmaf(Mx[14],s2, fmaf(Mx[15],s3, fmaf(Nx[6],ux, Nx[7]*uy)))));

#define AFF4(Mx, s0,s1,s2,s3, c0,c1,c2,c3, n0,n1,n2,n3)                          \
  n0 = fmaf(Mx[0],s0,  fmaf(Mx[1],s1,  fmaf(Mx[2],s2,  fmaf(Mx[3],s3,  c0))));  \
  n1 = fmaf(Mx[4],s0,  fmaf(Mx[5],s1,  fmaf(Mx[6],s2,  fmaf(Mx[7],s3,  c1))));  \
  n2 = fmaf(Mx[8],s0,  fmaf(Mx[9],s1,  fmaf(Mx[10],s2, fmaf(Mx[11],s3, c2))));  \
  n3 = fmaf(Mx[12],s0, fmaf(Mx[13],s1, fmaf(Mx[14],s2, fmaf(Mx[15],s3, c3))));

// ---------- setup: build discrete-time (M, N) and powers in fp64 ----------
__device__ __forceinline__ void mm4d(const double* X, const double* Y, double* Z) {
  for (int i = 0; i < 4; ++i)
    for (int j = 0; j < 4; ++j) {
      double s = 0.0;
      for (int l = 0; l < 4; ++l) s += X[i*4+l] * Y[l*4+j];
      Z[i*4+j] = s;
    }
}

// ws layout (floats): [0:16) M, [16:24) N, [24:40) ML=M^LS, [40:56) MG=ML^per
__global__ void k_setup(const float* __restrict__ cin, const float* __restrict__ min_,
                        const float* __restrict__ kin, const float* __restrict__ dtin,
                        float* __restrict__ ws, int per) {
  double c1 = cin[0], c2 = cin[1], c3 = cin[2];
  double m1 = min_[0], m2 = min_[1];
  double k1 = kin[0], k2 = kin[1], k3 = kin[2];
  double h  = dtin[0];

  double A[16] = { 0.0, 1.0, 0.0, 0.0,
                  -(k1+k2)/m1, -(c1+c2)/m1,  k2/m1,  c2/m1,
                   0.0, 0.0, 0.0, 1.0,
                   k2/m2,  c2/m2, -(k3+k2)/m2, -(c3+c2)/m2 };

  double Q[16], R[16], S[16], M[16], tmp[16];
  for (int i = 0; i < 16; ++i) Q[i] = ((i % 5 == 0) ? 1.0 : 0.0) + (h/4.0)*A[i];
  mm4d(A, Q, tmp);
  for (int i = 0; i < 16; ++i) R[i] = ((i % 5 == 0) ? 1.0 : 0.0) + (h/3.0)*tmp[i];
  mm4d(A, R, tmp);
  for (int i = 0; i < 16; ++i) S[i] = ((i % 5 == 0) ? 1.0 : 0.0) + (h/2.0)*tmp[i];
  mm4d(A, S, tmp);
  for (int i = 0; i < 16; ++i) M[i] = ((i % 5 == 0) ? 1.0 : 0.0) + h*tmp[i];

  // N = h * S * B, with B columns [0,1/m1,0,0] and [0,0,0,1/m2]
  double N[8];
  for (int i = 0; i < 4; ++i) {
    N[2*i+0] = h * S[i*4+1] / m1;
    N[2*i+1] = h * S[i*4+3] / m2;
  }

  // ML = M^LS  (LS = 32 = 2^5)
  double P[16]; for (int i = 0; i < 16; ++i) P[i] = M[i];
  for (int r = 0; r < 5; ++r) { mm4d(P, P, tmp); for (int i = 0; i < 16; ++i) P[i] = tmp[i]; }

  // MG = ML^per (square-and-multiply)
  double G[16]; for (int i = 0; i < 16; ++i) G[i] = ((i % 5 == 0) ? 1.0 : 0.0);
  double Bs[16]; for (int i = 0; i < 16; ++i) Bs[i] = P[i];
  int e = per;
  while (e) {
    if (e & 1) { mm4d(G, Bs, tmp); for (int i = 0; i < 16; ++i) G[i] = tmp[i]; }
    mm4d(Bs, Bs, tmp); for (int i = 0; i < 16; ++i) Bs[i] = tmp[i];
    e >>= 1;
  }

  for (int i = 0; i < 16; ++i) ws[i]      = (float)M[i];
  for (int i = 0; i < 8;  ++i) ws[16+i]   = (float)N[i];
  for (int i = 0; i < 16; ++i) ws[24+i]   = (float)P[i];
  for (int i = 0; i < 16; ++i) ws[40+i]   = (float)G[i];
}

// ---------- pass1: per-chunk affine offset b over LS steps ----------
__launch_bounds__(BLK)
__global__ void k_pass1(const float4* __restrict__ u4, const float* __restrict__ ws,
                        float4* __restrict__ bout, int T2) {
  __shared__ float2 tile[BLK * 33];   // 33: +1 float2 pad -> 4-way bank aliasing only
  const int tid   = threadIdx.x;
  const int base2 = blockIdx.x * SPB; // float2 index of block's first step

  float Mm[16], Nn[8];
  #pragma unroll
  for (int i = 0; i < 16; ++i) Mm[i] = ws[i];
  #pragma unroll
  for (int i = 0; i < 8;  ++i) Nn[i] = ws[16+i];

  // stage block's u region coalesced into LDS (zeros past T)
  #pragma unroll
  for (int kk = 0; kk < LS/2; ++kk) {
    int idx4 = tid + kk*BLK;
    int p0 = base2 + 2*idx4;                     // even; T2 even -> one check covers float4
    float4 v = make_float4(0.f, 0.f, 0.f, 0.f);
    if (p0 < T2) v = u4[(base2 >> 1) + idx4];
    int l = 2*idx4, r = l >> 5, e = l & 31;
    tile[r*33 + e]     = make_float2(v.x, v.y);
    tile[r*33 + e + 1] = make_float2(v.z, v.w);
  }
  __syncthreads();

  float b0 = 0.f, b1 = 0.f, b2 = 0.f, b3 = 0.f;
  #pragma unroll
  for (int j = 0; j < LS; ++j) {
    float2 uu = tile[tid*33 + j];
    float n0, n1, n2, n3;
    STEP4(Mm, Nn, b0, b1, b2, b3, uu.x, uu.y, n0, n1, n2, n3);
    b0 = n0; b1 = n1; b2 = n2; b3 = n3;
  }
  bout[blockIdx.x * BLK + tid] = make_float4(b0, b1, b2, b3);
}

// ---------- scan: chunk transforms -> chunk start states (in-place) ----------
__launch_bounds__(SCAN_T)
__global__ void k_scan(const float* __restrict__ ws, float4* __restrict__ bx,
                       const float* __restrict__ x0in, int nchunk, int per) {
  __shared__ float4 Bt[SCAN_T];
  __shared__ float4 Xs[SCAN_T];
  const int t = threadIdx.x;

  float ML[16];
  #pragma unroll
  for (int i = 0; i < 16; ++i) ML[i] = ws[24+i];

  const int s = t * per;
  const int e = min(nchunk, s + per);

  // phase A: composed offset over my chunk group
  float a0 = 0.f, a1 = 0.f, a2 = 0.f, a3 = 0.f;
  for (int c = s; c < e; ++c) {
    float4 bb = bx[c];
    float n0, n1, n2, n3;
    AFF4(ML, a0, a1, a2, a3, bb.x, bb.y, bb.z, bb.w, n0, n1, n2, n3);
    a0 = n0; a1 = n1; a2 = n2; a3 = n3;
  }
  Bt[t] = make_float4(a0, a1, a2, a3);
  __syncthreads();

  // phase B: serial scan over 256 groups on thread 0 (matrix MG = ML^per)
  if (t == 0) {
    float MG[16];
    #pragma unroll
    for (int i = 0; i < 16; ++i) MG[i] = ws[40+i];
    float X0 = x0in[0], X1 = x0in[1], X2 = x0in[2], X3 = x0in[3];
    for (int g = 0; g < SCAN_T; ++g) {
      Xs[g] = make_float4(X0, X1, X2, X3);
      float4 bb = Bt[g];
      float n0, n1, n2, n3;
      AFF4(MG, X0, X1, X2, X3, bb.x, bb.y, bb.z, bb.w, n0, n1, n2, n3);
      X0 = n0; X1 = n1; X2 = n2; X3 = n3;
    }
  }
  __syncthreads();

  // phase C: emit per-chunk start states (overwrite bx in place)
  float4 xs = Xs[t];
  a0 = xs.x; a1 = xs.y; a2 = xs.z; a3 = xs.w;
  for (int c = s; c < e; ++c) {
    float4 bb = bx[c];
    bx[c] = make_float4(a0, a1, a2, a3);
    float n0, n1, n2, n3;
    AFF4(ML, a0, a1, a2, a3, bb.x, bb.y, bb.z, bb.w, n0, n1, n2, n3);
    a0 = n0; a1 = n1; a2 = n2; a3 = n3;
  }
}

// ---------- pass3: replay chunks from start states, emit (z1,z2) ----------
__launch_bounds__(BLK)
__global__ void k_pass3(const float4* __restrict__ u4, const float* __restrict__ ws,
                        const float4* __restrict__ xstart, float4* __restrict__ out4, int T2) {
  __shared__ float2 tile[BLK * 33];
  const int tid   = threadIdx.x;
  const int base2 = blockIdx.x * SPB;

  float Mm[16], Nn[8];
  #pragma unroll
  for (int i = 0; i < 16; ++i) Mm[i] = ws[i];
  #pragma unroll
  for (int i = 0; i < 8;  ++i) Nn[i] = ws[16+i];

  #pragma unroll
  for (int kk = 0; kk < LS/2; ++kk) {
    int idx4 = tid + kk*BLK;
    int p0 = base2 + 2*idx4;
    float4 v = make_float4(0.f, 0.f, 0.f, 0.f);
    if (p0 < T2) v = u4[(base2 >> 1) + idx4];
    int l = 2*idx4, r = l >> 5, e = l & 31;
    tile[r*33 + e]     = make_float2(v.x, v.y);
    tile[r*33 + e + 1] = make_float2(v.z, v.w);
  }
  __syncthreads();

  float4 xs = xstart[blockIdx.x * BLK + tid];
  float x0 = xs.x, x1 = xs.y, x2 = xs.z, x3 = xs.w;
  #pragma unroll
  for (int j = 0; j < LS; ++j) {
    float2 uu = tile[tid*33 + j];
    float n0, n1, n2, n3;
    STEP4(Mm, Nn, x0, x1, x2, x3, uu.x, uu.y, n0, n1, n2, n3);
    x0 = n0; x1 = n1; x2 = n2; x3 = n3;
    tile[tid*33 + j] = make_float2(x0, x2);  // y_t = (z1, z2), in-place over consumed u
  }
  __syncthreads();

  #pragma unroll
  for (int kk = 0; kk < LS/2; ++kk) {
    int idx4 = tid + kk*BLK;
    int p0 = base2 + 2*idx4;
    if (p0 < T2) {
      int l = 2*idx4, r = l >> 5, e = l & 31;
      float2 a = tile[r*33 + e];
      float2 b = tile[r*33 + e + 1];
      out4[(base2 >> 1) + idx4] = make_float4(a.x, a.y, b.x, b.y);
    }
  }
}

extern "C" void kernel_launch(void* const* d_in, const int* in_sizes, int n_in,
                              void* d_out, int out_size, void* d_ws, size_t ws_size,
                              hipStream_t stream) {
  const float* u   = (const float*)d_in[0];
  const float* x0  = (const float*)d_in[1];
  const float* cc  = (const float*)d_in[2];
  const float* mm  = (const float*)d_in[3];
  const float* kk  = (const float*)d_in[4];
  const float* dt  = (const float*)d_in[5];

  const int T2     = in_sizes[0] / 2;                 // timesteps (float2 count of u)
  const int nblk   = (T2 + SPB - 1) / SPB;            // 489 for T=2e6
  const int nchunk = nblk * BLK;                      // 62592
  const int per    = (nchunk + SCAN_T - 1) / SCAN_T;  // 245

  float*  ws   = (float*)d_ws;                        // consts: 56 floats (64 reserved)
  float4* bbuf = (float4*)(ws + 64);                  // nchunk float4 (~1 MB)

  k_setup<<<1, 1, 0, stream>>>(cc, mm, kk, dt, ws, per);
  k_pass1<<<nblk, BLK, 0, stream>>>((const float4*)u, ws, bbuf, T2);
  k_scan<<<1, SCAN_T, 0, stream>>>(ws, bbuf, x0, nchunk, per);
  k_pass3<<<nblk, BLK, 0, stream>>>((const float4*)u, ws, bbuf, (float4*)d_out, T2);
}

// Round 2
// 104.019 us; speedup vs baseline: 2.4492x; 2.4492x over previous
//
#include <hip/hip_runtime.h>

#define BLK 128            // threads per block (2 waves)
#define LS  32             // timesteps per thread-chunk
#define SPB (BLK*LS)       // timesteps per block = 4096
#define MID_T 512          // threads in mid-scan block

// ws float offsets: [0:16) M, [16:24) N, [24+16k) SK[k]=M^(32*2^k) k=0..7,
//                   [152+16k) GK[k]=M^(4096*2^k) k=0..8  -> 296 floats, reserve 320
#define WS_M   0
#define WS_N   16
#define WS_SK  24
#define WS_GK  152
#define WS_RES 320

// ---------- affine step macros (row-major M[16], N[8]) ----------
#define STEP4(Mx,Nx, s0,s1,s2,s3, ux,uy, n0,n1,n2,n3)                                              \
  n0 = fmaf(Mx[0],s0,  fmaf(Mx[1],s1,  fmaf(Mx[2],s2,  fmaf(Mx[3],s3,  fmaf(Nx[0],ux, Nx[1]*uy))))); \
  n1 = fmaf(Mx[4],s0,  fmaf(Mx[5],s1,  fmaf(Mx[6],s2,  fmaf(Mx[7],s3,  fmaf(Nx[2],ux, Nx[3]*uy))))); \
  n2 = fmaf(Mx[8],s0,  fmaf(Mx[9],s1,  fmaf(Mx[10],s2, fmaf(Mx[11],s3, fmaf(Nx[4],ux, Nx[5]*uy))))); \
  n3 = fmaf(Mx[12],s0, fmaf(Mx[13],s1, fmaf(Mx[14],s2, fmaf(Mx[15],s3, fmaf(Nx[6],ux, Nx[7]*uy)))));

__device__ __forceinline__ float4 aff_apply(const float* Mx, float4 l, float4 c) {
  float4 r;
  r.x = fmaf(Mx[0],l.x,  fmaf(Mx[1],l.y,  fmaf(Mx[2],l.z,  fmaf(Mx[3],l.w,  c.x))));
  r.y = fmaf(Mx[4],l.x,  fmaf(Mx[5],l.y,  fmaf(Mx[6],l.z,  fmaf(Mx[7],l.w,  c.y))));
  r.z = fmaf(Mx[8],l.x,  fmaf(Mx[9],l.y,  fmaf(Mx[10],l.z, fmaf(Mx[11],l.w, c.z))));
  r.w = fmaf(Mx[12],l.x, fmaf(Mx[13],l.y, fmaf(Mx[14],l.z, fmaf(Mx[15],l.w, c.w))));
  return r;
}

// ---------- setup: build discrete-time (M, N) and powers in fp64 ----------
__device__ __forceinline__ void mm4d(const double* X, const double* Y, double* Z) {
  for (int i = 0; i < 4; ++i)
    for (int j = 0; j < 4; ++j) {
      double s = 0.0;
      for (int l = 0; l < 4; ++l) s += X[i*4+l] * Y[l*4+j];
      Z[i*4+j] = s;
    }
}

__global__ void k_setup(const float* __restrict__ cin, const float* __restrict__ min_,
                        const float* __restrict__ kin, const float* __restrict__ dtin,
                        float* __restrict__ ws) {
  double c1 = cin[0], c2 = cin[1], c3 = cin[2];
  double m1 = min_[0], m2 = min_[1];
  double k1 = kin[0], k2 = kin[1], k3 = kin[2];
  double h  = dtin[0];

  double A[16] = { 0.0, 1.0, 0.0, 0.0,
                  -(k1+k2)/m1, -(c1+c2)/m1,  k2/m1,  c2/m1,
                   0.0, 0.0, 0.0, 1.0,
                   k2/m2,  c2/m2, -(k3+k2)/m2, -(c3+c2)/m2 };

  double Q[16], R[16], S[16], M[16], tmp[16];
  for (int i = 0; i < 16; ++i) Q[i] = ((i % 5 == 0) ? 1.0 : 0.0) + (h/4.0)*A[i];
  mm4d(A, Q, tmp);
  for (int i = 0; i < 16; ++i) R[i] = ((i % 5 == 0) ? 1.0 : 0.0) + (h/3.0)*tmp[i];
  mm4d(A, R, tmp);
  for (int i = 0; i < 16; ++i) S[i] = ((i % 5 == 0) ? 1.0 : 0.0) + (h/2.0)*tmp[i];
  mm4d(A, S, tmp);
  for (int i = 0; i < 16; ++i) M[i] = ((i % 5 == 0) ? 1.0 : 0.0) + h*tmp[i];

  // N = h * S * B, with B columns [0,1/m1,0,0] and [0,0,0,1/m2]
  double N[8];
  for (int i = 0; i < 4; ++i) {
    N[2*i+0] = h * S[i*4+1] / m1;
    N[2*i+1] = h * S[i*4+3] / m2;
  }

  for (int i = 0; i < 16; ++i) ws[WS_M+i] = (float)M[i];
  for (int i = 0; i < 8;  ++i) ws[WS_N+i] = (float)N[i];

  // P = M^32 (5 squarings)
  double P[16]; for (int i = 0; i < 16; ++i) P[i] = M[i];
  for (int r = 0; r < 5; ++r) { mm4d(P, P, tmp); for (int i = 0; i < 16; ++i) P[i] = tmp[i]; }

  // SK[k] = M^(32*2^k), k=0..7
  for (int i = 0; i < 16; ++i) ws[WS_SK+i] = (float)P[i];
  for (int k = 1; k < 8; ++k) {
    mm4d(P, P, tmp); for (int i = 0; i < 16; ++i) P[i] = tmp[i];
    for (int i = 0; i < 16; ++i) ws[WS_SK+16*k+i] = (float)P[i];
  }
  // now P = M^4096. GK[k] = M^(4096*2^k), k=0..8
  for (int i = 0; i < 16; ++i) ws[WS_GK+i] = (float)P[i];
  for (int k = 1; k < 9; ++k) {
    mm4d(P, P, tmp); for (int i = 0; i < 16; ++i) P[i] = tmp[i];
    for (int i = 0; i < 16; ++i) ws[WS_GK+16*k+i] = (float)P[i];
  }
}

// ---------- pass1: per-chunk offset b + in-block scan -> block aggregate ----------
__launch_bounds__(BLK)
__global__ void k_pass1(const float4* __restrict__ u4, const float* __restrict__ ws,
                        float4* __restrict__ bout, float4* __restrict__ aggout, int T2) {
  __shared__ float2 tile[BLK * 33];   // +1 float2 pad per 32-step row
  __shared__ float4 S1[BLK];
  __shared__ float  SKs[8*16];
  const int tid   = threadIdx.x;
  const int base2 = blockIdx.x * SPB;

  float Mm[16], Nn[8];
  #pragma unroll
  for (int i = 0; i < 16; ++i) Mm[i] = ws[WS_M+i];
  #pragma unroll
  for (int i = 0; i < 8;  ++i) Nn[i] = ws[WS_N+i];
  if (tid < 128) SKs[tid] = ws[WS_SK + tid];

  // stage block's u region coalesced into LDS (zeros past T)
  #pragma unroll
  for (int kk = 0; kk < LS/2; ++kk) {
    int idx4 = tid + kk*BLK;
    int p0 = base2 + 2*idx4;
    float4 v = make_float4(0.f, 0.f, 0.f, 0.f);
    if (p0 < T2) v = u4[(base2 >> 1) + idx4];
    int l = 2*idx4, r = l >> 5, e = l & 31;
    tile[r*33 + e]     = make_float2(v.x, v.y);
    tile[r*33 + e + 1] = make_float2(v.z, v.w);
  }
  __syncthreads();

  float b0 = 0.f, b1 = 0.f, b2 = 0.f, b3 = 0.f;
  #pragma unroll
  for (int j = 0; j < LS; ++j) {
    float2 uu = tile[tid*33 + j];
    float n0, n1, n2, n3;
    STEP4(Mm, Nn, b0, b1, b2, b3, uu.x, uu.y, n0, n1, n2, n3);
    b0 = n0; b1 = n1; b2 = n2; b3 = n3;
  }
  float4 b = make_float4(b0, b1, b2, b3);
  bout[blockIdx.x * BLK + tid] = b;

  // in-block Hillis-Steele over 128 chunk offsets -> aggregate at index 127
  S1[tid] = b;
  __syncthreads();
  for (int k = 0; k < 7; ++k) {
    int off = 1 << k;
    float4 l, c;
    bool act = (tid >= off);
    if (act) { l = S1[tid - off]; c = S1[tid]; }
    __syncthreads();
    if (act) S1[tid] = aff_apply(&SKs[16*k], l, c);
    __syncthreads();
  }
  if (tid == BLK-1) aggout[blockIdx.x] = S1[BLK-1];
}

// ---------- mid: log-depth scan of [x0, agg_0..agg_{nblk-1}] -> block start states ----------
__launch_bounds__(MID_T)
__global__ void k_mid(const float* __restrict__ ws, float4* __restrict__ agg,
                      const float* __restrict__ x0in, int nblk) {
  __shared__ float4 A[MID_T];     // n = nblk+1 <= 512 elements
  __shared__ float  GKs[9*16];
  const int t = threadIdx.x;
  const int n = nblk + 1;

  if (t < 144) GKs[t] = ws[WS_GK + t];
  if (t == 0)      A[0] = make_float4(x0in[0], x0in[1], x0in[2], x0in[3]);
  else if (t < n)  A[t] = agg[t-1];
  __syncthreads();

  for (int k = 0; k < 9; ++k) {
    int off = 1 << k;
    if (off >= n) break;
    float4 l, c;
    bool act = (t >= off && t < n);
    if (act) { l = A[t - off]; c = A[t]; }
    __syncthreads();
    if (act) A[t] = aff_apply(&GKs[16*k], l, c);
    __syncthreads();
  }
  if (t < nblk) agg[t] = A[t];   // state at start of block t (in-place overwrite)
}

// ---------- pass3: in-block scan -> per-thread start state, replay, emit (z1,z2) ----------
__launch_bounds__(BLK)
__global__ void k_pass3(const float4* __restrict__ u4, const float* __restrict__ ws,
                        const float4* __restrict__ bbuf, const float4* __restrict__ xbs,
                        float4* __restrict__ out4, int T2) {
  __shared__ float2 tile[BLK * 33];
  __shared__ float4 S3[BLK + 1];
  __shared__ float  SKs[8*16];
  const int tid   = threadIdx.x;
  const int base2 = blockIdx.x * SPB;

  float Mm[16], Nn[8];
  #pragma unroll
  for (int i = 0; i < 16; ++i) Mm[i] = ws[WS_M+i];
  #pragma unroll
  for (int i = 0; i < 8;  ++i) Nn[i] = ws[WS_N+i];
  if (tid < 128) SKs[tid] = ws[WS_SK + tid];

  #pragma unroll
  for (int kk = 0; kk < LS/2; ++kk) {
    int idx4 = tid + kk*BLK;
    int p0 = base2 + 2*idx4;
    float4 v = make_float4(0.f, 0.f, 0.f, 0.f);
    if (p0 < T2) v = u4[(base2 >> 1) + idx4];
    int l = 2*idx4, r = l >> 5, e = l & 31;
    tile[r*33 + e]     = make_float2(v.x, v.y);
    tile[r*33 + e + 1] = make_float2(v.z, v.w);
  }

  // scan elements: S3[0] = block start state, S3[j+1] = chunk j offset
  if (tid == 0) S3[0] = xbs[blockIdx.x];
  S3[tid + 1] = bbuf[blockIdx.x * BLK + tid];
  __syncthreads();

  // Hillis-Steele over 129 elements; thread tid owns element tid+1
  for (int k = 0; k < 8; ++k) {
    int off = 1 << k;
    int i = tid + 1;
    float4 l, c;
    bool act = (i >= off);
    if (act) { l = S3[i - off]; c = S3[i]; }
    __syncthreads();
    if (act) S3[i] = aff_apply(&SKs[16*k], l, c);
    __syncthreads();
  }

  float4 xs = S3[tid];   // state at start of chunk tid
  float x0 = xs.x, x1 = xs.y, x2 = xs.z, x3 = xs.w;
  #pragma unroll
  for (int j = 0; j < LS; ++j) {
    float2 uu = tile[tid*33 + j];
    float n0, n1, n2, n3;
    STEP4(Mm, Nn, x0, x1, x2, x3, uu.x, uu.y, n0, n1, n2, n3);
    x0 = n0; x1 = n1; x2 = n2; x3 = n3;
    tile[tid*33 + j] = make_float2(x0, x2);  // y_t = (z1, z2)
  }
  __syncthreads();

  #pragma unroll
  for (int kk = 0; kk < LS/2; ++kk) {
    int idx4 = tid + kk*BLK;
    int p0 = base2 + 2*idx4;
    if (p0 < T2) {
      int l = 2*idx4, r = l >> 5, e = l & 31;
      float2 a = tile[r*33 + e];
      float2 b = tile[r*33 + e + 1];
      out4[(base2 >> 1) + idx4] = make_float4(a.x, a.y, b.x, b.y);
    }
  }
}

extern "C" void kernel_launch(void* const* d_in, const int* in_sizes, int n_in,
                              void* d_out, int out_size, void* d_ws, size_t ws_size,
                              hipStream_t stream) {
  const float* u   = (const float*)d_in[0];
  const float* x0  = (const float*)d_in[1];
  const float* cc  = (const float*)d_in[2];
  const float* mm  = (const float*)d_in[3];
  const float* kk  = (const float*)d_in[4];
  const float* dt  = (const float*)d_in[5];

  const int T2     = in_sizes[0] / 2;          // timesteps
  const int nblk   = (T2 + SPB - 1) / SPB;     // 489 for T=2e6 (nblk+1 <= 512 required)
  const int nchunk = nblk * BLK;

  float*  ws   = (float*)d_ws;
  float4* bbuf = (float4*)(ws + WS_RES);       // nchunk float4 (~1 MB)
  float4* abuf = bbuf + nchunk;                // nblk float4 (aggregates -> start states)

  k_setup<<<1, 1, 0, stream>>>(cc, mm, kk, dt, ws);
  k_pass1<<<nblk, BLK, 0, stream>>>((const float4*)u, ws, bbuf, abuf, T2);
  k_mid  <<<1, MID_T, 0, stream>>>(ws, abuf, x0, nblk);
  k_pass3<<<nblk, BLK, 0, stream>>>((const float4*)u, ws, bbuf, abuf, (float4*)d_out, T2);
}